// Round 6
// baseline (389.356 us; speedup 1.0000x reference)
//
#include <hip/hip_runtime.h>

// Modulated deformable conv, fp32 in/out. B=4, CIN=COUT=256, H=W=64, KS=3, PAD=1.
// R6: fused kernel, 256-thr blocks (4 waves), M=16 px, grid 1024 (~5 blocks/CU).
// Tap-major K (chunk = 32 cins, k = tap*32+cl), sampling params hoisted to regs,
// bilinear corner pairs fetched as one 8B load.
// ws: wfrag = bf16 B-fragments, w_conv 589,824 + w_off 73,728 shorts = 1.33 MB.

#define WOFF_FRAG_OFF 589824

using short8 = __attribute__((ext_vector_type(8))) short;
using f32x4  = __attribute__((ext_vector_type(4))) float;

struct __attribute__((packed, aligned(4))) pairf { float x, y; };  // 4B-aligned 8B load

__device__ inline unsigned short f2bf(float v) {
    unsigned u = __float_as_uint(v);
    unsigned r = u + 0x7fffu + ((u >> 16) & 1u);   // RNE (inputs finite)
    return (unsigned short)(r >> 16);
}

// tap-major k_new -> original k: chunk=k/288, tap=(k%288)>>5, cl=(k%288)&31
__device__ inline int k_orig_of(int k_new) {
    const int chunk = k_new / 288;
    const int rem   = k_new - chunk * 288;
    const int tap   = rem >> 5;
    const int cl    = rem & 31;
    return ((chunk << 5) + cl) * 9 + tap;
}

// Swizzle w_conv / w_off into MFMA B-fragment order (bf16) with tap-major K.
__global__ __launch_bounds__(256) void k_prep(
    const float* __restrict__ w_conv,
    const float* __restrict__ w_off,
    unsigned short* __restrict__ wfrag)
{
    const int i = blockIdx.x * 256 + threadIdx.x;   // grid covers 663,552 exactly
    if (i < WOFF_FRAG_OFF) {
        const int j    = i & 7;
        const int lane = (i >> 3) & 63;
        const int nt   = (i >> 9) & 15;
        const int kt   = i >> 13;                    // 0..71
        const int n = nt * 16 + (lane & 15);
        const int k_new = kt * 32 + ((lane >> 4) << 3) + j;
        wfrag[i] = f2bf(w_conv[n * 2304 + k_orig_of(k_new)]);
    } else {
        const int i2 = i - WOFF_FRAG_OFF;
        const int j    = i2 & 7;
        const int lane = (i2 >> 3) & 63;
        const int nt   = (i2 >> 9) & 1;
        const int kt   = i2 >> 10;                   // 0..71
        const int n = nt * 16 + (lane & 15);
        const int k_new = kt * 32 + ((lane >> 4) << 3) + j;
        wfrag[i] = (n < 27) ? f2bf(w_off[n * 2304 + k_orig_of(k_new)])
                            : (unsigned short)0;
    }
}

__global__ __launch_bounds__(256, 5) void k_all(
    const float* __restrict__ x,
    const float* __restrict__ b_off,
    const unsigned short* __restrict__ wfrag,
    float* __restrict__ out)
{
    __shared__ short As[16 * 296];                   // 9472 B; row stride 296 shorts
    __shared__ __align__(16) float4 pwt[160];        // [tap][px16] pair weights (padded)
    __shared__ __align__(16) int2   pidx[160];       // [tap][px16] row-pair indices
    __shared__ __align__(16) float  om_s[32 * 16];   // [c][px]

    const int bid = blockIdx.x;
    const int sid = ((bid & 7) << 7) | (bid >> 3);   // XCD-contiguous px bands
    const int m0  = sid << 4;
    const int b   = m0 >> 12;
    const int h   = (m0 >> 6) & 63;
    const int wbase = m0 & 63;                        // 0,16,32,48
    const int tid  = threadIdx.x;
    const int lane = tid & 63;
    const int wv   = tid >> 6;                        // 0..3
    const int quad = lane >> 4;
    const int px   = tid & 15;                        // staging pixel
    const int slot = tid >> 4;                        // 0..15, 18 k each
    const int kbase = slot * 18;

    const float* xb = x + ((size_t)b << 20);
    const unsigned short* woffb = wfrag + WOFF_FRAG_OFF;

    // ---------------- phase 1: offset conv via MFMA (regular im2col) ----------------
    f32x4 om_acc = {0.f, 0.f, 0.f, 0.f};
    const int nt_o = wv & 1;

    for (int chunk = 0; chunk < 8; ++chunk) {
        unsigned short sv0 = 0;
#pragma unroll
        for (int j = 0; j < 18; ++j) {
            const int k   = kbase + j;
            const int tap = k >> 5;
            const int cin = (chunk << 5) + (k & 31);
            const int ky  = (tap * 11) >> 5;          // tap/3 for tap<9
            const int kx  = tap - ky * 3;
            const int yy  = h + ky - 1;
            const int xx  = wbase + px + kx - 1;
            const bool v  = ((unsigned)yy < 64u) & ((unsigned)xx < 64u);
            const int idx = v ? (yy << 6) + xx : 0;
            float t = xb[((size_t)cin << 12) + idx];
            t = v ? t : 0.f;
            const unsigned short s = f2bf(t);
            if (j & 1)
                ((unsigned*)As)[px * 148 + slot * 9 + (j >> 1)] =
                    (unsigned)sv0 | ((unsigned)s << 16);
            else sv0 = s;
        }
        __syncthreads();
#pragma unroll
        for (int kt = 0; kt < 9; ++kt) {
            const int ktg = chunk * 9 + kt;
            const short8 a  = *(const short8*)&As[(lane & 15) * 296 + kt * 32 + quad * 8];
            const short8 bf = *(const short8*)(woffb + ((size_t)(ktg * 2 + nt_o) * 64 + lane) * 8);
            om_acc = __builtin_amdgcn_mfma_f32_16x16x32_bf16(a, bf, om_acc, 0, 0, 0);
        }
        __syncthreads();
    }
    if (wv < 2) {   // C-layout: row(px) = quad*4+reg, col(c) = nt*16 + (lane&15)
        const int c = (nt_o << 4) + (lane & 15);
        *(f32x4*)&om_s[c * 16 + (quad << 2)] = om_acc;
    }
    __syncthreads();

    // ---------------- phase 2: per-(tap,px) pair-gather params ----------------
    if (tid < 144) {
        const int p2 = tid & 15, tap = tid >> 4;
        const int ky = (tap * 11) >> 5, kx = tap - ky * 3;
        const float dyv = om_s[(2 * tap) * 16 + p2] + b_off[2 * tap];
        const float dxv = om_s[(2 * tap + 1) * 16 + p2] + b_off[2 * tap + 1];
        const float mo  = om_s[(18 + tap) * 16 + p2] + b_off[18 + tap];
        const float mv  = 1.f / (1.f + expf(-mo));
        const float py  = dyv + (float)(h - 1 + ky);
        const float pxf = dxv + (float)(wbase + p2 - 1 + kx);
        const float y0f = floorf(py), x0f = floorf(pxf);
        const float wy = py - y0f,    wx = pxf - x0f;
        const float vy0 = (y0f >=  0.f && y0f <= 63.f) ? 1.f : 0.f;
        const float vy1 = (y0f >= -1.f && y0f <= 62.f) ? 1.f : 0.f;
        const int ry0 = (int)fminf(fmaxf(y0f, 0.f), 63.f);
        const int ry1 = (int)fminf(fmaxf(y0f + 1.f, 0.f), 63.f);
        const float rw0 = (1.f - wy) * vy0 * mv;
        const float rw1 = wy * vy1 * mv;
        // pair loaded at bx = clamp(x0f,0,62): weights for (.x,.y)
        const bool in01 = (x0f >= 0.f && x0f <= 62.f);
        const float wa = in01 ? (1.f - wx) : ((x0f == -1.f) ? wx : 0.f);
        const float wb = in01 ? wx : ((x0f == 63.f) ? (1.f - wx) : 0.f);
        const int bx = (int)fminf(fmaxf(x0f, 0.f), 62.f);
        pwt[tid]  = make_float4(wa, wb, rw0, rw1);
        pidx[tid] = make_int2(ry0 * 64 + bx, ry1 * 64 + bx);
    }
    __syncthreads();

    // ---------------- phase 3: deformable sampling + main GEMM ----------------
    f32x4 acc[4];
#pragma unroll
    for (int nn = 0; nn < 4; ++nn) acc[nn] = f32x4{0.f, 0.f, 0.f, 0.f};

    // hoist this thread's (<=2) tap params into registers — chunk-invariant
    const int jb0 = 32 - (kbase & 31);
    const int jb  = jb0 > 18 ? 18 : jb0;              // j >= jb -> tap tA+1
    const int tA  = kbase >> 5;
    const float4 wtA = pwt[tA * 16 + px];
    const float4 wtB = pwt[(tA + 1) * 16 + px];       // padded; unused if jb==18
    const int2   iA  = pidx[tA * 16 + px];
    const int2   iB  = pidx[(tA + 1) * 16 + px];

    for (int chunk = 0; chunk < 8; ++chunk) {
        unsigned short sv0 = 0;
#pragma unroll
        for (int j = 0; j < 18; ++j) {
            const bool useB = (j >= jb);
            const float4 wt = useB ? wtB : wtA;
            const int2   ii = useB ? iB : iA;
            const int cin = (chunk << 5) + ((kbase + j) & 31);
            const float* p = xb + ((size_t)cin << 12);
            const pairf p0 = *(const pairf*)(p + ii.x);
            const pairf p1 = *(const pairf*)(p + ii.y);
            const float t0 = p0.x * wt.x + p0.y * wt.y;
            const float t1 = p1.x * wt.x + p1.y * wt.y;
            const float v  = t0 * wt.z + t1 * wt.w;
            const unsigned short s = f2bf(v);
            if (j & 1)
                ((unsigned*)As)[px * 148 + slot * 9 + (j >> 1)] =
                    (unsigned)sv0 | ((unsigned)s << 16);
            else sv0 = s;
        }
        __syncthreads();
#pragma unroll
        for (int kt = 0; kt < 9; ++kt) {
            const int ktg = chunk * 9 + kt;
            const short8 a = *(const short8*)&As[(lane & 15) * 296 + kt * 32 + quad * 8];
            const unsigned short* wbp = wfrag + (((size_t)ktg * 16 + (wv << 2)) * 64 + lane) * 8;
#pragma unroll
            for (int nn = 0; nn < 4; ++nn) {
                const short8 bf = *(const short8*)(wbp + nn * 512);
                acc[nn] = __builtin_amdgcn_mfma_f32_16x16x32_bf16(a, bf, acc[nn], 0, 0, 0);
            }
        }
        __syncthreads();
    }

    // epilogue: C/D row = quad*4+reg (local px -> w), col = lane&15 (cout)
#pragma unroll
    for (int nn = 0; nn < 4; ++nn) {
        const int n = (wv << 6) + (nn << 4) + (lane & 15);
        float* op = out + (((size_t)((b << 8) + n)) << 12) + (h << 6) + wbase + (quad << 2);
        *(f32x4*)op = acc[nn];
    }
}

extern "C" void kernel_launch(void* const* d_in, const int* in_sizes, int n_in,
                              void* d_out, int out_size, void* d_ws, size_t ws_size,
                              hipStream_t stream) {
    const float* x      = (const float*)d_in[0];
    const float* w_off  = (const float*)d_in[1];
    const float* b_off  = (const float*)d_in[2];
    const float* w_conv = (const float*)d_in[3];
    float* out = (float*)d_out;

    unsigned short* wfrag = (unsigned short*)d_ws;   // 663,552 shorts = 1.33 MB

    hipLaunchKernelGGL(k_prep, dim3(2592), dim3(256), 0, stream,
                       w_conv, w_off, wfrag);
    hipLaunchKernelGGL(k_all, dim3(1024), dim3(256), 0, stream,
                       x, b_off, wfrag, out);
}

// Round 7
// 313.578 us; speedup vs baseline: 1.2417x; 1.2417x over previous
//
#include <hip/hip_runtime.h>

// Modulated deformable conv, fp32 in/out. B=4, CIN=COUT=256, H=W=64, KS=3, PAD=1.
// R7: R5 shell (512-thr blocks, 32 px, grid 512, launch_bounds(512,4) -> 128 VGPR cap)
// + R6's verified wins: tap-major K, register-hoisted sampling params, pair-gathers.
// ws: wfrag = bf16 B-fragments, w_conv 589,824 + w_off 73,728 shorts = 1.33 MB.

#define WOFF_FRAG_OFF 589824

using short8 = __attribute__((ext_vector_type(8))) short;
using f32x4  = __attribute__((ext_vector_type(4))) float;

struct __attribute__((packed, aligned(4))) pairf { float x, y; };

__device__ inline unsigned short f2bf(float v) {
    unsigned u = __float_as_uint(v);
    unsigned r = u + 0x7fffu + ((u >> 16) & 1u);   // RNE (inputs finite)
    return (unsigned short)(r >> 16);
}

// tap-major k_new -> original k: chunk=k/288, tap=(k%288)>>5, cl=(k%288)&31
__device__ inline int k_orig_of(int k_new) {
    const int chunk = k_new / 288;
    const int rem   = k_new - chunk * 288;
    const int tap   = rem >> 5;
    const int cl    = rem & 31;
    return ((chunk << 5) + cl) * 9 + tap;
}

// Swizzle w_conv / w_off into MFMA B-fragment order (bf16), tap-major K. (HW-verified R6)
__global__ __launch_bounds__(256) void k_prep(
    const float* __restrict__ w_conv,
    const float* __restrict__ w_off,
    unsigned short* __restrict__ wfrag)
{
    const int i = blockIdx.x * 256 + threadIdx.x;   // grid covers 663,552 exactly
    if (i < WOFF_FRAG_OFF) {
        const int j    = i & 7;
        const int lane = (i >> 3) & 63;
        const int nt   = (i >> 9) & 15;
        const int kt   = i >> 13;                    // 0..71
        const int n = nt * 16 + (lane & 15);
        const int k_new = kt * 32 + ((lane >> 4) << 3) + j;
        wfrag[i] = f2bf(w_conv[n * 2304 + k_orig_of(k_new)]);
    } else {
        const int i2 = i - WOFF_FRAG_OFF;
        const int j    = i2 & 7;
        const int lane = (i2 >> 3) & 63;
        const int nt   = (i2 >> 9) & 1;
        const int kt   = i2 >> 10;                   // 0..71
        const int n = nt * 16 + (lane & 15);
        const int k_new = kt * 32 + ((lane >> 4) << 3) + j;
        wfrag[i] = (n < 27) ? f2bf(w_off[n * 2304 + k_orig_of(k_new)])
                            : (unsigned short)0;
    }
}

__global__ __launch_bounds__(512, 4) void k_all(
    const float* __restrict__ x,
    const float* __restrict__ b_off,
    const unsigned short* __restrict__ wfrag,
    float* __restrict__ out)
{
    __shared__ short As[32 * 296];                    // 18,944 B; px stride 296 shorts
    __shared__ __align__(16) float4 pwt[10 * 32];     // [tap][px32], tap=9 = zero pad
    __shared__ __align__(16) int2   pidx[10 * 32];
    __shared__ __align__(16) float  om_s[32 * 32];    // [c][px]

    const int bid = blockIdx.x;
    const int sid = ((bid & 7) << 6) | (bid >> 3);    // XCD-contiguous px bands
    const int m0  = sid << 5;
    const int b   = m0 >> 12;
    const int h   = (m0 >> 6) & 63;
    const int wbase = m0 & 63;                         // 0 or 32
    const int tid  = threadIdx.x;
    const int lane = tid & 63;
    const int wv   = tid >> 6;                         // 0..7
    const int quad = lane >> 4;
    const int px   = tid & 31;                         // staging pixel
    const int slot = tid >> 5;                         // 0..15, 18 k each
    const int kbase = slot * 18;

    const float* xb = x + ((size_t)b << 20);
    const unsigned short* woffb = wfrag + WOFF_FRAG_OFF;

    // ---------------- phase 1: offset conv via MFMA (regular im2col) ----------------
    f32x4 om_acc[2];
    om_acc[0] = f32x4{0.f, 0.f, 0.f, 0.f};
    om_acc[1] = f32x4{0.f, 0.f, 0.f, 0.f};
    const int nt_o = wv & 1;

    for (int chunk = 0; chunk < 8; ++chunk) {
        unsigned short sv0 = 0;
#pragma unroll
        for (int j = 0; j < 18; ++j) {
            const int k   = kbase + j;
            const int tap = k >> 5;
            const int cin = (chunk << 5) + (k & 31);
            const int ky  = (tap * 11) >> 5;           // tap/3 for tap<9
            const int kx  = tap - ky * 3;
            const int yy  = h + ky - 1;
            const int xx  = wbase + px + kx - 1;
            const bool v  = ((unsigned)yy < 64u) & ((unsigned)xx < 64u);
            const int idx = v ? (yy << 6) + xx : 0;
            float t = xb[((size_t)cin << 12) + idx];
            t = v ? t : 0.f;
            const unsigned short s = f2bf(t);
            if (j & 1)
                ((unsigned*)As)[px * 148 + slot * 9 + (j >> 1)] =
                    (unsigned)sv0 | ((unsigned)s << 16);
            else sv0 = s;
        }
        __syncthreads();
#pragma unroll
        for (int kt = 0; kt < 9; ++kt) {
            const int ktg = chunk * 9 + kt;
            const short8 a0 = *(const short8*)&As[(lane & 15) * 296 + kt * 32 + quad * 8];
            const short8 a1 = *(const short8*)&As[((lane & 15) + 16) * 296 + kt * 32 + quad * 8];
            const short8 bf = *(const short8*)(woffb + ((size_t)(ktg * 2 + nt_o) * 64 + lane) * 8);
            om_acc[0] = __builtin_amdgcn_mfma_f32_16x16x32_bf16(a0, bf, om_acc[0], 0, 0, 0);
            om_acc[1] = __builtin_amdgcn_mfma_f32_16x16x32_bf16(a1, bf, om_acc[1], 0, 0, 0);
        }
        __syncthreads();
    }
    if (wv < 2) {   // C-layout: row(px) = ms*16 + quad*4+reg, col(c) = nt*16 + (lane&15)
        const int c = (nt_o << 4) + (lane & 15);
#pragma unroll
        for (int ms = 0; ms < 2; ++ms)
            *(f32x4*)&om_s[c * 32 + (ms << 4) + (quad << 2)] = om_acc[ms];
    }
    __syncthreads();

    // ---------------- phase 2: per-(tap,px) pair-gather params ----------------
    if (tid < 288) {
        const int p2 = tid & 31, tap = tid >> 5;
        const int ky = (tap * 11) >> 5, kx = tap - ky * 3;
        const float dyv = om_s[(2 * tap) * 32 + p2] + b_off[2 * tap];
        const float dxv = om_s[(2 * tap + 1) * 32 + p2] + b_off[2 * tap + 1];
        const float mo  = om_s[(18 + tap) * 32 + p2] + b_off[18 + tap];
        const float mv  = 1.f / (1.f + expf(-mo));
        const float py  = dyv + (float)(h - 1 + ky);
        const float pxf = dxv + (float)(wbase + p2 - 1 + kx);
        const float y0f = floorf(py), x0f = floorf(pxf);
        const float wy = py - y0f,    wx = pxf - x0f;
        const float vy0 = (y0f >=  0.f && y0f <= 63.f) ? 1.f : 0.f;
        const float vy1 = (y0f >= -1.f && y0f <= 62.f) ? 1.f : 0.f;
        const int ry0 = (int)fminf(fmaxf(y0f, 0.f), 63.f);
        const int ry1 = (int)fminf(fmaxf(y0f + 1.f, 0.f), 63.f);
        const float rw0 = (1.f - wy) * vy0 * mv;
        const float rw1 = wy * vy1 * mv;
        // pair loaded at bx = clamp(x0f,0,62): weights for (.x,.y)  [HW-verified R6]
        const bool in01 = (x0f >= 0.f && x0f <= 62.f);
        const float wa = in01 ? (1.f - wx) : ((x0f == -1.f) ? wx : 0.f);
        const float wb = in01 ? wx : ((x0f == 63.f) ? (1.f - wx) : 0.f);
        const int bx = (int)fminf(fmaxf(x0f, 0.f), 62.f);
        pwt[tid]  = make_float4(wa, wb, rw0, rw1);
        pidx[tid] = make_int2(ry0 * 64 + bx, ry1 * 64 + bx);
    } else if (tid < 320) {                            // zero the tap=9 pad row
        pwt[tid]  = make_float4(0.f, 0.f, 0.f, 0.f);
        pidx[tid] = make_int2(0, 0);
    }
    __syncthreads();

    // ---------------- phase 3: deformable sampling + main GEMM ----------------
    f32x4 acc[2][2];
#pragma unroll
    for (int a = 0; a < 2; ++a)
#pragma unroll
        for (int c = 0; c < 2; ++c) acc[a][c] = f32x4{0.f, 0.f, 0.f, 0.f};

    const int n0 = wv << 5;                            // wave's first cout

    // hoist this thread's (<=2) tap params into registers — chunk-invariant
    const int jb0 = 32 - (kbase & 31);
    const int jb  = jb0 > 18 ? 18 : jb0;               // j >= jb -> tap tA+1
    const int tA  = kbase >> 5;
    const float4 wtA = pwt[tA * 32 + px];
    const float4 wtB = pwt[(tA + 1) * 32 + px];        // tap=9 pad is zeroed
    const int2   iA  = pidx[tA * 32 + px];
    const int2   iB  = pidx[(tA + 1) * 32 + px];

    for (int chunk = 0; chunk < 8; ++chunk) {
        unsigned short sv0 = 0;
#pragma unroll
        for (int j = 0; j < 18; ++j) {
            const bool useB = (j >= jb);
            const float4 wt = useB ? wtB : wtA;
            const int2   ii = useB ? iB : iA;
            const int cin = (chunk << 5) + ((kbase + j) & 31);
            const float* p = xb + ((size_t)cin << 12);
            const pairf p0 = *(const pairf*)(p + ii.x);
            const pairf p1 = *(const pairf*)(p + ii.y);
            const float t0 = p0.x * wt.x + p0.y * wt.y;
            const float t1 = p1.x * wt.x + p1.y * wt.y;
            const float v  = t0 * wt.z + t1 * wt.w;
            const unsigned short s = f2bf(v);
            if (j & 1)
                ((unsigned*)As)[px * 148 + slot * 9 + (j >> 1)] =
                    (unsigned)sv0 | ((unsigned)s << 16);
            else sv0 = s;
        }
        __syncthreads();
#pragma unroll
        for (int kt = 0; kt < 9; ++kt) {
            const int ktg = chunk * 9 + kt;
            const short8 a0 = *(const short8*)&As[(lane & 15) * 296 + kt * 32 + quad * 8];
            const short8 a1 = *(const short8*)&As[((lane & 15) + 16) * 296 + kt * 32 + quad * 8];
            const unsigned short* wbp = wfrag + (((size_t)ktg * 16 + (n0 >> 4)) * 64 + lane) * 8;
#pragma unroll
            for (int nn = 0; nn < 2; ++nn) {
                const short8 bf = *(const short8*)(wbp + nn * 512);
                acc[0][nn] = __builtin_amdgcn_mfma_f32_16x16x32_bf16(a0, bf, acc[0][nn], 0, 0, 0);
                acc[1][nn] = __builtin_amdgcn_mfma_f32_16x16x32_bf16(a1, bf, acc[1][nn], 0, 0, 0);
            }
        }
        __syncthreads();
    }

    // epilogue: C/D row = quad*4+reg (local px -> w), col = lane&15 (cout)
#pragma unroll
    for (int ms = 0; ms < 2; ++ms) {
        const int wq = wbase + (ms << 4) + (quad << 2);
#pragma unroll
        for (int nn = 0; nn < 2; ++nn) {
            const int n = n0 + (nn << 4) + (lane & 15);
            float* op = out + (((size_t)((b << 8) + n)) << 12) + (h << 6) + wq;
            *(f32x4*)op = acc[ms][nn];
        }
    }
}

extern "C" void kernel_launch(void* const* d_in, const int* in_sizes, int n_in,
                              void* d_out, int out_size, void* d_ws, size_t ws_size,
                              hipStream_t stream) {
    const float* x      = (const float*)d_in[0];
    const float* w_off  = (const float*)d_in[1];
    const float* b_off  = (const float*)d_in[2];
    const float* w_conv = (const float*)d_in[3];
    float* out = (float*)d_out;

    unsigned short* wfrag = (unsigned short*)d_ws;   // 663,552 shorts = 1.33 MB

    hipLaunchKernelGGL(k_prep, dim3(2592), dim3(256), 0, stream,
                       w_conv, w_off, wfrag);
    hipLaunchKernelGGL(k_all, dim3(512), dim3(512), 0, stream,
                       x, b_off, wfrag, out);
}

// Round 8
// 176.302 us; speedup vs baseline: 2.2085x; 1.7786x over previous
//
#include <hip/hip_runtime.h>

// Modulated deformable conv, fp32 in/out. B=4, CIN=COUT=256, H=W=64, KS=3, PAD=1.
// R8: tap-outer K (k_new = tap*256 + cin; each 32-wide kt-tile = one tap).
// Per-tap staging: one param set per thread, no per-sample tap decode.
// Double-buffered A-slab, one barrier per tap. unroll-4 sampling (anti-spill).
// ws: wfrag = bf16 B-fragments, w_conv 589,824 + w_off 73,728 shorts = 1.33 MB.

#define WOFF_FRAG_OFF 589824

using short8 = __attribute__((ext_vector_type(8))) short;
using f32x4  = __attribute__((ext_vector_type(4))) float;

struct __attribute__((packed, aligned(4))) pairf { float x, y; };

__device__ inline unsigned short f2bf(float v) {
    unsigned u = __float_as_uint(v);
    unsigned r = u + 0x7fffu + ((u >> 16) & 1u);   // RNE (inputs finite)
    return (unsigned short)(r >> 16);
}

// Swizzle w_conv / w_off into MFMA B-fragment order (bf16), tap-outer K:
// k_new = tap*256 + cin  ->  k_orig = cin*9 + tap.
__global__ __launch_bounds__(256) void k_prep(
    const float* __restrict__ w_conv,
    const float* __restrict__ w_off,
    unsigned short* __restrict__ wfrag)
{
    const int i = blockIdx.x * 256 + threadIdx.x;   // grid covers 663,552 exactly
    if (i < WOFF_FRAG_OFF) {
        const int j    = i & 7;
        const int lane = (i >> 3) & 63;
        const int nt   = (i >> 9) & 15;
        const int kt   = i >> 13;                    // 0..71
        const int n = nt * 16 + (lane & 15);
        const int k_new = kt * 32 + ((lane >> 4) << 3) + j;
        const int k_orig = (k_new & 255) * 9 + (k_new >> 8);
        wfrag[i] = f2bf(w_conv[n * 2304 + k_orig]);
    } else {
        const int i2 = i - WOFF_FRAG_OFF;
        const int j    = i2 & 7;
        const int lane = (i2 >> 3) & 63;
        const int nt   = (i2 >> 9) & 1;
        const int kt   = i2 >> 10;                   // 0..71
        const int n = nt * 16 + (lane & 15);
        const int k_new = kt * 32 + ((lane >> 4) << 3) + j;
        const int k_orig = (k_new & 255) * 9 + (k_new >> 8);
        wfrag[i] = (n < 27) ? f2bf(w_off[n * 2304 + k_orig])
                            : (unsigned short)0;
    }
}

__global__ __launch_bounds__(512, 4) void k_all(
    const float* __restrict__ x,
    const float* __restrict__ b_off,
    const unsigned short* __restrict__ wfrag,
    float* __restrict__ out)
{
    // A-slab: [buf][px][k_local=cin], px stride 264 shorts (528 B = 16B mult,
    // b128 row reads land 2-way bank-aliased = free).
    __shared__ short As[2][32 * 264];                 // 33,792 B
    __shared__ __align__(16) float4 pwt[9 * 32];      // [tap][px]
    __shared__ __align__(16) int2   pidx[9 * 32];
    __shared__ __align__(16) float  om_s[32 * 32];    // [c][px]

    const int bid = blockIdx.x;
    const int sid = ((bid & 7) << 6) | (bid >> 3);    // XCD-contiguous px bands
    const int m0  = sid << 5;
    const int b   = m0 >> 12;
    const int h   = (m0 >> 6) & 63;
    const int wbase = m0 & 63;                         // 0 or 32
    const int tid  = threadIdx.x;
    const int lane = tid & 63;
    const int wv   = tid >> 6;                         // 0..7
    const int quad = lane >> 4;
    const int px   = tid & 31;                         // staging pixel
    const int slot = tid >> 5;                         // 0..15: 16 cins each

    const float* xb = x + ((size_t)b << 20);
    const unsigned short* woffb = wfrag + WOFF_FRAG_OFF;

    // -------- phase 1: offset conv via MFMA, tap-outer, double-buffered --------
    f32x4 om_acc[2];
    om_acc[0] = f32x4{0.f, 0.f, 0.f, 0.f};
    om_acc[1] = f32x4{0.f, 0.f, 0.f, 0.f};
    const int nt_o = wv & 1;

    auto stage_reg = [&](int tap, int bufi) {
        const int ky = (tap * 11) >> 5;                // tap/3 for tap<9
        const int kx = tap - ky * 3;
        const int yy = h + ky - 1;
        const int xx = wbase + px + kx - 1;
        const bool v = ((unsigned)yy < 64u) & ((unsigned)xx < 64u);
        const int idx = v ? (yy << 6) + xx : 0;
        const float* p = xb + idx;
        unsigned* dst = (unsigned*)&As[bufi][0] + px * 132 + slot * 8;
#pragma unroll 4
        for (int i = 0; i < 8; ++i) {
            const int cin0 = (slot << 4) + i * 2;
            float t0 = p[(size_t)cin0 << 12];
            float t1 = p[((size_t)cin0 + 1) << 12];
            t0 = v ? t0 : 0.f;
            t1 = v ? t1 : 0.f;
            dst[i] = (unsigned)f2bf(t0) | ((unsigned)f2bf(t1) << 16);
        }
    };

    stage_reg(0, 0);
    __syncthreads();
    for (int tap = 0; tap < 9; ++tap) {
        if (tap < 8) stage_reg(tap + 1, (tap + 1) & 1);
        const short* cur = &As[tap & 1][0];
#pragma unroll
        for (int kt = 0; kt < 8; ++kt) {
            const int ktg = tap * 8 + kt;
            const short8 a0 = *(const short8*)&cur[(lane & 15) * 264 + kt * 32 + quad * 8];
            const short8 a1 = *(const short8*)&cur[((lane & 15) + 16) * 264 + kt * 32 + quad * 8];
            const short8 bf = *(const short8*)(woffb + ((size_t)(ktg * 2 + nt_o) * 64 + lane) * 8);
            om_acc[0] = __builtin_amdgcn_mfma_f32_16x16x32_bf16(a0, bf, om_acc[0], 0, 0, 0);
            om_acc[1] = __builtin_amdgcn_mfma_f32_16x16x32_bf16(a1, bf, om_acc[1], 0, 0, 0);
        }
        __syncthreads();
    }
    if (wv < 2) {   // C-layout: row(px) = ms*16 + quad*4+reg, col(c) = nt*16+(lane&15)
        const int c = (nt_o << 4) + (lane & 15);
#pragma unroll
        for (int ms = 0; ms < 2; ++ms)
            *(f32x4*)&om_s[c * 32 + (ms << 4) + (quad << 2)] = om_acc[ms];
    }
    __syncthreads();

    // -------- phase 2: per-(tap,px) pair-gather params (HW-verified R6/R7) --------
    if (tid < 288) {
        const int p2 = tid & 31, tap = tid >> 5;
        const int ky = (tap * 11) >> 5, kx = tap - ky * 3;
        const float dyv = om_s[(2 * tap) * 32 + p2] + b_off[2 * tap];
        const float dxv = om_s[(2 * tap + 1) * 32 + p2] + b_off[2 * tap + 1];
        const float mo  = om_s[(18 + tap) * 32 + p2] + b_off[18 + tap];
        const float mv  = 1.f / (1.f + expf(-mo));
        const float py  = dyv + (float)(h - 1 + ky);
        const float pxf = dxv + (float)(wbase + p2 - 1 + kx);
        const float y0f = floorf(py), x0f = floorf(pxf);
        const float wy = py - y0f,    wx = pxf - x0f;
        const float vy0 = (y0f >=  0.f && y0f <= 63.f) ? 1.f : 0.f;
        const float vy1 = (y0f >= -1.f && y0f <= 62.f) ? 1.f : 0.f;
        const int ry0 = (int)fminf(fmaxf(y0f, 0.f), 63.f);
        const int ry1 = (int)fminf(fmaxf(y0f + 1.f, 0.f), 63.f);
        const float rw0 = (1.f - wy) * vy0 * mv;
        const float rw1 = wy * vy1 * mv;
        const bool in01 = (x0f >= 0.f && x0f <= 62.f);
        const float wa = in01 ? (1.f - wx) : ((x0f == -1.f) ? wx : 0.f);
        const float wb = in01 ? wx : ((x0f == 63.f) ? (1.f - wx) : 0.f);
        const int bx = (int)fminf(fmaxf(x0f, 0.f), 62.f);
        pwt[tid]  = make_float4(wa, wb, rw0, rw1);
        pidx[tid] = make_int2(ry0 * 64 + bx, ry1 * 64 + bx);
    }
    __syncthreads();

    // -------- phase 3: deformable sampling + main GEMM, tap-outer, dbuf --------
    f32x4 acc[2][2];
#pragma unroll
    for (int a = 0; a < 2; ++a)
#pragma unroll
        for (int c = 0; c < 2; ++c) acc[a][c] = f32x4{0.f, 0.f, 0.f, 0.f};

    const int n0 = wv << 5;                            // wave's first cout

    auto stage_def = [&](int tap, int bufi) {
        const float4 wt = pwt[tap * 32 + px];          // once per tap
        const int2   ii = pidx[tap * 32 + px];
        const float* p0b = xb + ii.x;
        const float* p1b = xb + ii.y;
        unsigned* dst = (unsigned*)&As[bufi][0] + px * 132 + slot * 8;
#pragma unroll 4
        for (int i = 0; i < 8; ++i) {
            const size_t c0 = (size_t)((slot << 4) + i * 2) << 12;
            const pairf a0 = *(const pairf*)(p0b + c0);
            const pairf b0 = *(const pairf*)(p1b + c0);
            const pairf a1 = *(const pairf*)(p0b + c0 + 4096);
            const pairf b1 = *(const pairf*)(p1b + c0 + 4096);
            const float v0 = (a0.x * wt.x + a0.y * wt.y) * wt.z
                           + (b0.x * wt.x + b0.y * wt.y) * wt.w;
            const float v1 = (a1.x * wt.x + a1.y * wt.y) * wt.z
                           + (b1.x * wt.x + b1.y * wt.y) * wt.w;
            dst[i] = (unsigned)f2bf(v0) | ((unsigned)f2bf(v1) << 16);
        }
    };

    stage_def(0, 0);
    __syncthreads();
    for (int tap = 0; tap < 9; ++tap) {
        if (tap < 8) stage_def(tap + 1, (tap + 1) & 1);
        const short* cur = &As[tap & 1][0];
#pragma unroll
        for (int kt = 0; kt < 8; ++kt) {
            const int ktg = tap * 8 + kt;
            const short8 a0 = *(const short8*)&cur[(lane & 15) * 264 + kt * 32 + quad * 8];
            const short8 a1 = *(const short8*)&cur[((lane & 15) + 16) * 264 + kt * 32 + quad * 8];
            const unsigned short* wbp = wfrag + (((size_t)ktg * 16 + (n0 >> 4)) * 64 + lane) * 8;
#pragma unroll
            for (int nn = 0; nn < 2; ++nn) {
                const short8 bf = *(const short8*)(wbp + nn * 512);
                acc[0][nn] = __builtin_amdgcn_mfma_f32_16x16x32_bf16(a0, bf, acc[0][nn], 0, 0, 0);
                acc[1][nn] = __builtin_amdgcn_mfma_f32_16x16x32_bf16(a1, bf, acc[1][nn], 0, 0, 0);
            }
        }
        __syncthreads();
    }

    // epilogue: C/D row = quad*4+reg (local px -> w), col = lane&15 (cout)
#pragma unroll
    for (int ms = 0; ms < 2; ++ms) {
        const int wq = wbase + (ms << 4) + (quad << 2);
#pragma unroll
        for (int nn = 0; nn < 2; ++nn) {
            const int n = n0 + (nn << 4) + (lane & 15);
            float* op = out + (((size_t)((b << 8) + n)) << 12) + (h << 6) + wq;
            *(f32x4*)op = acc[ms][nn];
        }
    }
}

extern "C" void kernel_launch(void* const* d_in, const int* in_sizes, int n_in,
                              void* d_out, int out_size, void* d_ws, size_t ws_size,
                              hipStream_t stream) {
    const float* x      = (const float*)d_in[0];
    const float* w_off  = (const float*)d_in[1];
    const float* b_off  = (const float*)d_in[2];
    const float* w_conv = (const float*)d_in[3];
    float* out = (float*)d_out;

    unsigned short* wfrag = (unsigned short*)d_ws;   // 663,552 shorts = 1.33 MB

    hipLaunchKernelGGL(k_prep, dim3(2592), dim3(256), 0, stream,
                       w_conv, w_off, wfrag);
    hipLaunchKernelGGL(k_all, dim3(512), dim3(512), 0, stream,
                       x, b_off, wfrag, out);
}